// Round 16
// baseline (666.458 us; speedup 1.0000x reference)
//
#include <hip/hip_runtime.h>
#include <hip/hip_bf16.h>

#define N_NODES_C 100000
#define N_GRAPHS_C 64
#define FDIM 128
#define NPB 512                 // nodes per bucket
#define NBUCK 196               // ceil(100000/512)
#define SB 256                  // scatter blocks
#define CAP 4096                // staged capacity per bucket (max expected ~3500)

typedef _Float16 half8v __attribute__((ext_vector_type(8)));
typedef __attribute__((ext_vector_type(4))) float f32x4;
typedef __attribute__((ext_vector_type(2))) float f32x2;

__device__ __forceinline__ unsigned short f2h(float f) {
    union { _Float16 h; unsigned short u; } v; v.h = (_Float16)f; return v.u;
}

__device__ __forceinline__ void acc8h(float* a, half8v v) {
#pragma unroll
    for (int j = 0; j < 8; ++j) a[j] += (float)v[j];
}

// fp8 e4m3 (OCP on gfx950) helpers
__device__ __forceinline__ unsigned pk4fp8(float a, float b, float c, float d) {
    int w = 0;
    w = __builtin_amdgcn_cvt_pk_fp8_f32(a, b, w, false);   // bytes 0,1
    w = __builtin_amdgcn_cvt_pk_fp8_f32(c, d, w, true);    // bytes 2,3
    return (unsigned)w;
}
// decode+accumulate 16 fp8 (one uint4 = 16B) into a[0..15]
__device__ __forceinline__ void acc16fp8(float* a, uint4 v) {
    f32x2 f;
    f = __builtin_amdgcn_cvt_pk_f32_fp8(v.x, false); a[0]  += f.x; a[1]  += f.y;
    f = __builtin_amdgcn_cvt_pk_f32_fp8(v.x, true);  a[2]  += f.x; a[3]  += f.y;
    f = __builtin_amdgcn_cvt_pk_f32_fp8(v.y, false); a[4]  += f.x; a[5]  += f.y;
    f = __builtin_amdgcn_cvt_pk_f32_fp8(v.y, true);  a[6]  += f.x; a[7]  += f.y;
    f = __builtin_amdgcn_cvt_pk_f32_fp8(v.z, false); a[8]  += f.x; a[9]  += f.y;
    f = __builtin_amdgcn_cvt_pk_f32_fp8(v.z, true);  a[10] += f.x; a[11] += f.y;
    f = __builtin_amdgcn_cvt_pk_f32_fp8(v.w, false); a[12] += f.x; a[13] += f.y;
    f = __builtin_amdgcn_cvt_pk_f32_fp8(v.w, true);  a[14] += f.x; a[15] += f.y;
}

// ================================================================ merged prep + scatter + finalize
// Block roles by blockIdx.x:
//   [0, NBUCK)                : bucket finalize — SPIN until all scatter blocks signal done.
//                               Deadlock-free under ANY dispatch order: only 196 spinners
//                               exist, far below resident-block capacity, so the 256
//                               scatter blocks always have slots to run.
//   [NBUCK, NBUCK+SB)         : bucket scatter (LDS hist -> batched atomic -> LDS-cursor)
//   [+SB, +128)               : W1 prep ; [+128): W2 prep
//   [..convBlocks)            : x -> fp16 B0 + fp8 B08
//   last                      : graph bounds + zero pa/ph
__device__ __forceinline__ void prep_w_body(const float* __restrict__ Wl,
                                            const float* __restrict__ Wr,
                                            unsigned short* __restrict__ outW, int id) {
    int c = id >> 9, i = id & 511;
    int l = i >> 3, e = i & 7;
    int khalf = c >> 5, nf = (c >> 2) & 7, ks4 = c & 3;
    int j = nf * 16 + (l & 15);
    int k = khalf * 128 + ks4 * 32 + ((l >> 4) << 3) + e;
    float w = (k < 128) ? Wl[k * 128 + j] : Wr[(k - 128) * 128 + j];
    outW[id] = f2h(w);
}

__global__ __launch_bounds__(256) void prep_scatter_fin(const int* __restrict__ src,
                                                        const int* __restrict__ tgt,
                                                        int* __restrict__ cur,
                                                        int* __restrict__ done,
                                                        uint2* __restrict__ staged, int E,
                                                        int2* __restrict__ rsbe,
                                                        float* __restrict__ invd,
                                                        int* __restrict__ csr,
                                                        const float* __restrict__ x,
                                                        unsigned short* __restrict__ B0,
                                                        unsigned char* __restrict__ B08, int n8,
                                                        const float* __restrict__ W1l,
                                                        const float* __restrict__ W1r,
                                                        unsigned short* __restrict__ wt1,
                                                        const float* __restrict__ W2l,
                                                        const float* __restrict__ W2r,
                                                        unsigned short* __restrict__ wt2,
                                                        const int* __restrict__ batch,
                                                        int* __restrict__ gstart,
                                                        float* __restrict__ gcnt,
                                                        float* __restrict__ pa,
                                                        float* __restrict__ ph,
                                                        int N, int convBlocks) {
    const int b = blockIdx.x;
    const int t = threadIdx.x;

    if (b < NBUCK) {
        // ---------------- finalize role: wait for all scatter blocks
        __shared__ int ready;
        if (t == 0) {
            while (*(volatile int*)done < SB) __builtin_amdgcn_s_sleep(8);
            ready = 1;
        }
        __syncthreads();
        (void)ready;
        __threadfence();   // acquire: see scatter blocks' staged/cur writes

        __shared__ int dcnt[NPB];
        __shared__ int pref[NPB];
        __shared__ int ts[256];
        const int s = b * CAP;
        const int e = s + min(cur[b], CAP);
        const int nb0 = b * NPB;
        const int nn = min(NPB, N - nb0);

        dcnt[t] = 0; dcnt[t + 256] = 0;
        __syncthreads();
        for (int i = s + t; i < e; i += 256)
            atomicAdd(&dcnt[(int)staged[i].x - nb0], 1);
        __syncthreads();

        int a0 = dcnt[2 * t], a1 = dcnt[2 * t + 1];
        ts[t] = a0 + a1;
        __syncthreads();
        for (int off = 1; off < 256; off <<= 1) {
            int u = (t >= off) ? ts[t - off] : 0;
            __syncthreads();
            ts[t] += u;
            __syncthreads();
        }
        int excl = (t > 0) ? ts[t - 1] : 0;
        pref[2 * t] = excl;
        pref[2 * t + 1] = excl + a0;
        __syncthreads();

        if (t < nn) {
            int bg = s + pref[t];
            rsbe[nb0 + t] = make_int2(bg, bg + dcnt[t]);
            invd[nb0 + t] = 1.0f / (float)max(dcnt[t], 1);
        }
        int t2 = t + 256;
        if (t2 < nn) {
            int bg = s + pref[t2];
            rsbe[nb0 + t2] = make_int2(bg, bg + dcnt[t2]);
            invd[nb0 + t2] = 1.0f / (float)max(dcnt[t2], 1);
        }
        __syncthreads();

        dcnt[t] = pref[t]; dcnt[t + 256] = pref[t + 256];
        __syncthreads();
        for (int i = s + t; i < e; i += 256) {
            uint2 p = staged[i];
            int r = atomicAdd(&dcnt[(int)p.x - nb0], 1);
            csr[s + r] = (int)p.y;
        }
    } else if (b < NBUCK + SB) {
        // ---------------- scatter role
        __shared__ int lcnt[NBUCK];
        __shared__ int lbase[NBUCK];
        const int blk = b - NBUCK;
        if (t < NBUCK) lcnt[t] = 0;
        __syncthreads();
        const int chunk = (E + SB - 1) / SB;
        const int base = blk * chunk;
        const int lim = min(E, base + chunk);
        for (int e = base + t; e < lim; e += 256)
            atomicAdd(&lcnt[tgt[e] >> 9], 1);
        __syncthreads();
        if (t < NBUCK) {
            int c = lcnt[t];
            lbase[t] = c ? atomicAdd(&cur[t], c) : 0;
            lcnt[t] = 0;                      // reuse as local cursor
        }
        __syncthreads();
        for (int e = base + t; e < lim; e += 256) {
            int tv = tgt[e];
            int bk = tv >> 9;
            int r = atomicAdd(&lcnt[bk], 1);
            int pos = lbase[bk] + r;
            if (pos < CAP) {
                uint2 p; p.x = (unsigned)tv; p.y = (unsigned)src[e];
                staged[(size_t)bk * CAP + pos] = p;
            }
        }
        // signal completion (release)
        __threadfence();
        __syncthreads();
        if (t == 0) atomicAdd(done, 1);
    } else if (b < NBUCK + SB + 128) {
        prep_w_body(W1l, W1r, wt1, (b - NBUCK - SB) * 256 + t);
    } else if (b < NBUCK + SB + 256) {
        prep_w_body(W2l, W2r, wt2, (b - NBUCK - SB - 128) * 256 + t);
    } else if (b < NBUCK + SB + 256 + convBlocks) {
        int i = (b - NBUCK - SB - 256) * 256 + t;
        if (i < n8) {
            float4 v0 = *(const float4*)(x + (size_t)i * 8);
            float4 v1 = *(const float4*)(x + (size_t)i * 8 + 4);
            half8v o;
            o[0] = (_Float16)v0.x; o[1] = (_Float16)v0.y; o[2] = (_Float16)v0.z; o[3] = (_Float16)v0.w;
            o[4] = (_Float16)v1.x; o[5] = (_Float16)v1.y; o[6] = (_Float16)v1.z; o[7] = (_Float16)v1.w;
            *(half8v*)(B0 + (size_t)i * 8) = o;
            uint2 p8;
            p8.x = pk4fp8(v0.x, v0.y, v0.z, v0.w);
            p8.y = pk4fp8(v1.x, v1.y, v1.z, v1.w);
            *(uint2*)(B08 + (size_t)i * 8) = p8;
        }
    } else {
        if (t < 64) {
            int g = t;
            int lo = 0, hi = N;
            while (lo < hi) { int m = (lo + hi) >> 1; if (batch[m] < g) lo = m + 1; else hi = m; }
            int lb = lo;
            lo = 0; hi = N;
            while (lo < hi) { int m = (lo + hi) >> 1; if (batch[m] < g + 1) lo = m + 1; else hi = m; }
            gstart[g] = lb;
            gcnt[g] = (float)(lo - lb);
            if (g == 0) gstart[64] = N;
        }
        for (int i = t; i < N_GRAPHS_C * FDIM; i += 256) { pa[i] = 0.f; ph[i] = 0.f; }
    }
}

// ================================================================ fused SAGE layer (R15 structure)
__global__ __launch_bounds__(512) void sage_layer(const unsigned short* __restrict__ Xin,
                                                  const unsigned char* __restrict__ X8in,
                                                  const unsigned short* __restrict__ WtF,
                                                  const float* __restrict__ bias,
                                                  const int* __restrict__ csr,
                                                  const int2* __restrict__ rsbe,
                                                  const float* __restrict__ invd,
                                                  unsigned short* __restrict__ Hout,
                                                  unsigned char* __restrict__ H8out, int N) {
    __shared__ unsigned short atile[128 * 128];   // 32 KiB agg tile, 16B-chunk XOR swizzle
    __shared__ unsigned short wlds[32 * 512];     // 32 KiB, one khalf of W

    const int t = threadIdx.x;
    const int r0 = blockIdx.x * 128;

    // stage W khalf0 (hidden under agg phase)
#pragma unroll
    for (int rep = 0; rep < 4; ++rep) {
        int e = rep * 4096 + t * 8;
        *(half8v*)&wlds[e] = *(const half8v*)(WtF + e);
    }

    // ---- aggregate phase: 64 groups x 8 lanes; 2 rows per group; fp8 gathers @8 req/row
    {
        const int grp = t >> 3, lane = t & 7;
#pragma unroll
        for (int it = 0; it < 2; ++it) {
            const int row = it * 64 + grp;        // 0..127
            const int node = r0 + row;
            float a[16];
#pragma unroll
            for (int j = 0; j < 16; ++j) a[j] = 0.f;
            if (node < N) {
                const int2 be = rsbe[node];
                const int beg = be.x, end = be.y;
                for (int base = beg; base < end; base += 8) {
                    const int cnt = end - base;   // >= 1
                    int idx[8];
#pragma unroll
                    for (int k = 0; k < 8; ++k) idx[k] = csr[min(base + k, end - 1)];
                    uint4 v[8];
#pragma unroll
                    for (int k = 0; k < 8; ++k) {
                        if (k < cnt)
                            v[k] = *(const uint4*)(X8in + ((size_t)idx[k] << 7) + lane * 16);
                    }
#pragma unroll
                    for (int k = 0; k < 8; ++k) {
                        if (k < cnt) acc16fp8(a, v[k]);
                    }
                }
                float sc = invd[node];
#pragma unroll
                for (int j = 0; j < 16; ++j) a[j] *= sc;
            }
            half8v o0, o1;
#pragma unroll
            for (int j = 0; j < 8; ++j) { o0[j] = (_Float16)a[j]; o1[j] = (_Float16)a[8 + j]; }
            const int c0 = (2 * lane) ^ (row & 7);      // 16B-chunk XOR swizzle
            const int c1 = (2 * lane + 1) ^ (row & 7);
            *(half8v*)&atile[row * 128 + c0 * 8] = o0;
            *(half8v*)&atile[row * 128 + c1 * 8] = o1;
        }
    }
    __syncthreads();   // atile ready AND wlds khalf0 ready

    const int wave = t >> 6, l = t & 63;
    const int trow = wave * 16 + (l & 15);        // row within tile / D^T node-row
    const int lk = (l >> 4) << 3;

    f32x4 acc[8];
#pragma unroll
    for (int nf = 0; nf < 8; ++nf) acc[nf] = (f32x4)(0.f);

    // khalf0: A = agg tile (LDS, swizzled), W = wlds
#pragma unroll
    for (int ks4 = 0; ks4 < 4; ++ks4) {
        const int chunk = (ks4 * 4 + (l >> 4)) ^ (trow & 7);
        half8v af = *(const half8v*)&atile[trow * 128 + chunk * 8];
#pragma unroll
        for (int nf = 0; nf < 8; ++nf) {
            half8v bh = *(const half8v*)&wlds[(nf * 4 + ks4) * 512 + l * 8];
            acc[nf] = __builtin_amdgcn_mfma_f32_16x16x32_f16(bh, af, acc[nf], 0, 0, 0);
        }
    }
    __syncthreads();
    // stage W khalf1
#pragma unroll
    for (int rep = 0; rep < 4; ++rep) {
        int e = rep * 4096 + t * 8;
        *(half8v*)&wlds[e] = *(const half8v*)(WtF + 16384 + e);
    }
    __syncthreads();

    // khalf1: A = X rows from global (fp16)
    {
        int row = r0 + trow;
        if (row >= N) row = N - 1;                // clamp: only pollutes discarded rows
#pragma unroll
        for (int ks4 = 0; ks4 < 4; ++ks4) {
            half8v af = *(const half8v*)(Xin + ((size_t)row << 7) + ks4 * 32 + lk);
#pragma unroll
            for (int nf = 0; nf < 8; ++nf) {
                half8v bh = *(const half8v*)&wlds[(nf * 4 + ks4) * 512 + l * 8];
                acc[nf] = __builtin_amdgcn_mfma_f32_16x16x32_f16(bh, af, acc[nf], 0, 0, 0);
            }
        }
    }

    // epilogue: relu + fp16 stores (8B) + fp8 stores (4B)
    const int jb = (l >> 4) << 2;
    const int orow = r0 + trow;
    if (orow < N) {
#pragma unroll
        for (int nf = 0; nf < 8; ++nf) {
            float4 bv = *(const float4*)&bias[nf * 16 + jb];
            float o0 = fmaxf(acc[nf][0] + bv.x, 0.f);
            float o1 = fmaxf(acc[nf][1] + bv.y, 0.f);
            float o2 = fmaxf(acc[nf][2] + bv.z, 0.f);
            float o3 = fmaxf(acc[nf][3] + bv.w, 0.f);
            uint2 st;
            st.x = (unsigned)f2h(o0) | ((unsigned)f2h(o1) << 16);
            st.y = (unsigned)f2h(o2) | ((unsigned)f2h(o3) << 16);
            *(uint2*)(Hout + ((size_t)orow << 7) + nf * 16 + jb) = st;
            *(unsigned*)(H8out + ((size_t)orow << 7) + nf * 16 + jb) = pk4fp8(o0, o1, o2, o3);
        }
    }
}

// ================================================================ fused agg3 + pool + final readout
// Last-of-grid block (atomic ticket) runs the 64-row layer-3 GEMM + readout inline.
__global__ __launch_bounds__(256) void agg3_pool_final(const unsigned short* __restrict__ H2,
                                                       const unsigned char* __restrict__ H28,
                                                       const int* __restrict__ csr,
                                                       const int2* __restrict__ rsbe,
                                                       const float* __restrict__ invd,
                                                       const int* __restrict__ gstart,
                                                       float* __restrict__ pa,
                                                       float* __restrict__ ph,
                                                       int* __restrict__ pdone,
                                                       const float* __restrict__ gcnt,
                                                       const float* __restrict__ W3l,
                                                       const float* __restrict__ W3r,
                                                       const float* __restrict__ b3,
                                                       const float* __restrict__ Wout,
                                                       const float* __restrict__ bout,
                                                       float* __restrict__ out) {
    const int g = blockIdx.x >> 4;
    const int q = blockIdx.x & 15;
    const int s = gstart[g], e = gstart[g + 1];
    const int len = e - s;
    const int cs = s + (len * q) / 16;
    const int ce = s + (len * (q + 1)) / 16;
    const int t = threadIdx.x;
    const int grp = t >> 3, lane = t & 7;     // 32 groups x 8 lanes

    float aacc[16], hacc[16];
#pragma unroll
    for (int j = 0; j < 16; ++j) { aacc[j] = 0.f; hacc[j] = 0.f; }

    for (int node = cs + grp; node < ce; node += 32) {
        const int2 be = rsbe[node];
        const int beg = be.x, end = be.y;
        float a[16];
#pragma unroll
        for (int j = 0; j < 16; ++j) a[j] = 0.f;
        for (int base = beg; base < end; base += 8) {
            const int cnt = end - base;
            int idx[8];
#pragma unroll
            for (int k = 0; k < 8; ++k) idx[k] = csr[min(base + k, end - 1)];
            uint4 v[8];
#pragma unroll
            for (int k = 0; k < 8; ++k) {
                if (k < cnt)
                    v[k] = *(const uint4*)(H28 + ((size_t)idx[k] << 7) + lane * 16);
            }
#pragma unroll
            for (int k = 0; k < 8; ++k) {
                if (k < cnt) acc16fp8(a, v[k]);
            }
        }
        const float sc = invd[node];
#pragma unroll
        for (int j = 0; j < 16; ++j) aacc[j] += a[j] * sc;
        half8v own0 = *(const half8v*)(H2 + ((size_t)node << 7) + lane * 16);
        half8v own1 = *(const half8v*)(H2 + ((size_t)node << 7) + lane * 16 + 8);
        acc8h(hacc, own0);
        acc8h(hacc + 8, own1);
    }

    __shared__ float red[32][128];   // 16 KiB
#pragma unroll
    for (int j = 0; j < 16; ++j) red[grp][lane * 16 + j] = aacc[j];
    __syncthreads();
    if (t < 128) {
        float sum = 0.f;
#pragma unroll
        for (int k = 0; k < 32; ++k) sum += red[k][t];
        unsafeAtomicAdd(&pa[g * 128 + t], sum);
    }
    __syncthreads();
#pragma unroll
    for (int j = 0; j < 16; ++j) red[grp][lane * 16 + j] = hacc[j];
    __syncthreads();
    if (t < 128) {
        float sum = 0.f;
#pragma unroll
        for (int k = 0; k < 32; ++k) sum += red[k][t];
        unsafeAtomicAdd(&ph[g * 128 + t], sum);
    }

    // ---- last block performs the fp32 layer-3 GEMM + readout
    __shared__ int last;
    __threadfence();
    __syncthreads();
    if (t == 0) last = (atomicAdd(pdone, 1) == (int)gridDim.x - 1);
    __syncthreads();
    if (!last) return;
    __threadfence();   // acquire: see all blocks' pa/ph atomics

    __shared__ float sA[FDIM], sH[FDIM], sT[FDIM];
    for (int gg = 0; gg < N_GRAPHS_C; ++gg) {
        if (t < 128) {
            float inv = 1.0f / fmaxf(gcnt[gg], 1.0f);
            sA[t] = pa[gg * FDIM + t] * inv;
            sH[t] = ph[gg * FDIM + t] * inv;
        }
        __syncthreads();
        if (t < 128) {
            float acc = b3[t];
            for (int c = 0; c < FDIM; ++c)
                acc += sA[c] * W3l[c * FDIM + t] + sH[c] * W3r[c * FDIM + t];
            sT[t] = acc;
        }
        __syncthreads();
        if (t < 10) {
            float o = bout[t];
            for (int c = 0; c < FDIM; ++c) o += sT[c] * Wout[c * 10 + t];
            out[gg * 10 + t] = o;
        }
        __syncthreads();
    }
}

extern "C" void kernel_launch(void* const* d_in, const int* in_sizes, int n_in,
                              void* d_out, int out_size, void* d_ws, size_t ws_size,
                              hipStream_t stream) {
    const float* x     = (const float*)d_in[0];
    const int*   edge  = (const int*)d_in[1];
    const int*   batch = (const int*)d_in[2];
    const float* W1l = (const float*)d_in[3];
    const float* b1  = (const float*)d_in[4];
    const float* W1r = (const float*)d_in[5];
    const float* W2l = (const float*)d_in[6];
    const float* b2  = (const float*)d_in[7];
    const float* W2r = (const float*)d_in[8];
    const float* W3l = (const float*)d_in[9];
    const float* b3  = (const float*)d_in[10];
    const float* W3r = (const float*)d_in[11];
    const float* Wout = (const float*)d_in[12];
    const float* bout = (const float*)d_in[13];
    float* out = (float*)d_out;

    const int N = N_NODES_C;
    const int E = in_sizes[1] / 2;
    const int* src = edge;
    const int* tgt = edge + E;

    // ---- workspace layout
    char* ws = (char*)d_ws;
    size_t off = 0;
    auto carve = [&](size_t bytes) { char* p = ws + off; off += (bytes + 255) & ~(size_t)255; return p; };
    int2*  rsbe = (int2*)carve((size_t)N * 8);
    float* invd = (float*)carve((size_t)N * 4);
    int*   gstart = (int*)carve(65 * 4);
    float* gcnt = (float*)carve(64 * 4);
    float* pa   = (float*)carve((size_t)N_GRAPHS_C * FDIM * 4);
    float* ph   = (float*)carve((size_t)N_GRAPHS_C * FDIM * 4);
    int*   cur  = (int*)carve((NBUCK + 2) * 4);
    int*   done  = cur + NBUCK;
    int*   pdone = cur + NBUCK + 1;
    unsigned short* wt1 = (unsigned short*)carve(32768 * 2);
    unsigned short* wt2 = (unsigned short*)carve(32768 * 2);
    uint2* staged = (uint2*)carve((size_t)NBUCK * CAP * 8);
    int*   csr  = (int*)carve((size_t)NBUCK * CAP * 4);
    unsigned short* B0 = (unsigned short*)carve((size_t)N * FDIM * 2);
    unsigned short* B2 = (unsigned short*)carve((size_t)N * FDIM * 2);
    unsigned char* F0 = (unsigned char*)carve((size_t)N * FDIM);   // fp8 x -> later fp8 h2
    unsigned char* F1 = (unsigned char*)carve((size_t)N * FDIM);   // fp8 h1

    // ---- zero cursors + flags, then merged prep + scatter + finalize
    hipMemsetAsync(cur, 0, (NBUCK + 2) * 4, stream);
    const int n8 = N * FDIM / 8;
    const int convBlocks = (n8 + 255) / 256;
    prep_scatter_fin<<<NBUCK + SB + 256 + convBlocks + 1, 256, 0, stream>>>(
        src, tgt, cur, done, staged, E,
        rsbe, invd, csr,
        x, B0, F0, n8,
        W1l, W1r, wt1, W2l, W2r, wt2,
        batch, gstart, gcnt, pa, ph, N, convBlocks);

    const int layerGrid = (N + 127) / 128;

    // ---- layer 1 fused: h1 = relu([mean_N(x)|x]@W1+b1) -> B2 (fp16) + F1 (fp8)
    sage_layer<<<layerGrid, 512, 0, stream>>>(B0, F0, wt1, b1, csr, rsbe, invd, B2, F1, N);
    // ---- layer 2 fused: h2 = relu([mean_N(h1)|h1]@W2+b2) -> B0 (fp16) + F0 (fp8)
    sage_layer<<<layerGrid, 512, 0, stream>>>(B2, F1, wt2, b2, csr, rsbe, invd, B0, F0, N);

    // ---- layer 3 agg + pool + (last block) layer-3 GEMM + readout
    agg3_pool_final<<<N_GRAPHS_C * 16, 256, 0, stream>>>(B0, F0, csr, rsbe, invd, gstart,
                                                         pa, ph, pdone, gcnt,
                                                         W3l, W3r, b3, Wout, bout, out);
}

// Round 17
// 170.175 us; speedup vs baseline: 3.9163x; 3.9163x over previous
//
#include <hip/hip_runtime.h>
#include <hip/hip_bf16.h>

#define N_NODES_C 100000
#define N_GRAPHS_C 64
#define FDIM 128
#define NPB 512                 // nodes per bucket
#define NBUCK 196               // ceil(100000/512)
#define SB 256                  // scatter blocks
#define CAP 4096                // staged capacity per bucket (max expected ~3500)

typedef _Float16 half8v __attribute__((ext_vector_type(8)));
typedef __attribute__((ext_vector_type(4))) float f32x4;
typedef __attribute__((ext_vector_type(2))) float f32x2;

__device__ __forceinline__ unsigned short f2h(float f) {
    union { _Float16 h; unsigned short u; } v; v.h = (_Float16)f; return v.u;
}

__device__ __forceinline__ void acc8h(float* a, half8v v) {
#pragma unroll
    for (int j = 0; j < 8; ++j) a[j] += (float)v[j];
}

// fp8 e4m3 (OCP on gfx950) helpers
__device__ __forceinline__ unsigned pk4fp8(float a, float b, float c, float d) {
    int w = 0;
    w = __builtin_amdgcn_cvt_pk_fp8_f32(a, b, w, false);   // bytes 0,1
    w = __builtin_amdgcn_cvt_pk_fp8_f32(c, d, w, true);    // bytes 2,3
    return (unsigned)w;
}
// decode+accumulate 16 fp8 (one uint4 = 16B) into a[0..15]
__device__ __forceinline__ void acc16fp8(float* a, uint4 v) {
    f32x2 f;
    f = __builtin_amdgcn_cvt_pk_f32_fp8(v.x, false); a[0]  += f.x; a[1]  += f.y;
    f = __builtin_amdgcn_cvt_pk_f32_fp8(v.x, true);  a[2]  += f.x; a[3]  += f.y;
    f = __builtin_amdgcn_cvt_pk_f32_fp8(v.y, false); a[4]  += f.x; a[5]  += f.y;
    f = __builtin_amdgcn_cvt_pk_f32_fp8(v.y, true);  a[6]  += f.x; a[7]  += f.y;
    f = __builtin_amdgcn_cvt_pk_f32_fp8(v.z, false); a[8]  += f.x; a[9]  += f.y;
    f = __builtin_amdgcn_cvt_pk_f32_fp8(v.z, true);  a[10] += f.x; a[11] += f.y;
    f = __builtin_amdgcn_cvt_pk_f32_fp8(v.w, false); a[12] += f.x; a[13] += f.y;
    f = __builtin_amdgcn_cvt_pk_f32_fp8(v.w, true);  a[14] += f.x; a[15] += f.y;
}

// ================================================================ merged prep + bucket scatter
__device__ __forceinline__ void prep_w_body(const float* __restrict__ Wl,
                                            const float* __restrict__ Wr,
                                            unsigned short* __restrict__ outW, int id) {
    int c = id >> 9, i = id & 511;
    int l = i >> 3, e = i & 7;
    int khalf = c >> 5, nf = (c >> 2) & 7, ks4 = c & 3;
    int j = nf * 16 + (l & 15);
    int k = khalf * 128 + ks4 * 32 + ((l >> 4) << 3) + e;
    float w = (k < 128) ? Wl[k * 128 + j] : Wr[(k - 128) * 128 + j];
    outW[id] = f2h(w);
}

__global__ __launch_bounds__(256) void prep_scatter(const int* __restrict__ src,
                                                    const int* __restrict__ tgt,
                                                    int* __restrict__ cur,
                                                    uint2* __restrict__ staged, int E,
                                                    const float* __restrict__ x,
                                                    unsigned short* __restrict__ B0,
                                                    unsigned char* __restrict__ B08, int n8,
                                                    const float* __restrict__ W1l,
                                                    const float* __restrict__ W1r,
                                                    unsigned short* __restrict__ wt1,
                                                    const float* __restrict__ W2l,
                                                    const float* __restrict__ W2r,
                                                    unsigned short* __restrict__ wt2,
                                                    const int* __restrict__ batch,
                                                    int* __restrict__ gstart,
                                                    float* __restrict__ gcnt,
                                                    float* __restrict__ pa,
                                                    float* __restrict__ ph,
                                                    int nNodes, int convBlocks) {
    __shared__ int lcnt[NBUCK];
    __shared__ int lbase[NBUCK];
    const int b = blockIdx.x;
    const int t = threadIdx.x;

    if (b < SB) {
        if (t < NBUCK) lcnt[t] = 0;
        __syncthreads();
        const int chunk = (E + SB - 1) / SB;
        const int base = b * chunk;
        const int lim = min(E, base + chunk);
        for (int e = base + t; e < lim; e += 256)
            atomicAdd(&lcnt[tgt[e] >> 9], 1);
        __syncthreads();
        if (t < NBUCK) {
            int c = lcnt[t];
            lbase[t] = c ? atomicAdd(&cur[t], c) : 0;
            lcnt[t] = 0;                      // reuse as local cursor
        }
        __syncthreads();
        for (int e = base + t; e < lim; e += 256) {
            int tv = tgt[e];
            int bk = tv >> 9;
            int r = atomicAdd(&lcnt[bk], 1);
            int pos = lbase[bk] + r;
            if (pos < CAP) {
                uint2 p; p.x = (unsigned)tv; p.y = (unsigned)src[e];
                staged[(size_t)bk * CAP + pos] = p;
            }
        }
    } else if (b < SB + 128) {
        prep_w_body(W1l, W1r, wt1, (b - SB) * 256 + t);
    } else if (b < SB + 256) {
        prep_w_body(W2l, W2r, wt2, (b - SB - 128) * 256 + t);
    } else if (b < SB + 256 + convBlocks) {
        int i = (b - SB - 256) * 256 + t;
        if (i < n8) {
            float4 v0 = *(const float4*)(x + (size_t)i * 8);
            float4 v1 = *(const float4*)(x + (size_t)i * 8 + 4);
            half8v o;
            o[0] = (_Float16)v0.x; o[1] = (_Float16)v0.y; o[2] = (_Float16)v0.z; o[3] = (_Float16)v0.w;
            o[4] = (_Float16)v1.x; o[5] = (_Float16)v1.y; o[6] = (_Float16)v1.z; o[7] = (_Float16)v1.w;
            *(half8v*)(B0 + (size_t)i * 8) = o;
            uint2 p8;
            p8.x = pk4fp8(v0.x, v0.y, v0.z, v0.w);
            p8.y = pk4fp8(v1.x, v1.y, v1.z, v1.w);
            *(uint2*)(B08 + (size_t)i * 8) = p8;
        }
    } else {
        if (t < 64) {
            int g = t;
            int lo = 0, hi = nNodes;
            while (lo < hi) { int m = (lo + hi) >> 1; if (batch[m] < g) lo = m + 1; else hi = m; }
            int lb = lo;
            lo = 0; hi = nNodes;
            while (lo < hi) { int m = (lo + hi) >> 1; if (batch[m] < g + 1) lo = m + 1; else hi = m; }
            gstart[g] = lb;
            gcnt[g] = (float)(lo - lb);
            if (g == 0) gstart[64] = nNodes;
        }
        for (int i = t; i < N_GRAPHS_C * FDIM; i += 256) { pa[i] = 0.f; ph[i] = 0.f; }
    }
}

// ================================================================ bucket finalize
__global__ __launch_bounds__(256) void bucket_finalize(const uint2* __restrict__ staged,
                                                       const int* __restrict__ cur,
                                                       int2* __restrict__ rsbe,
                                                       float* __restrict__ invd,
                                                       int* __restrict__ csr, int N) {
    __shared__ int dcnt[NPB];
    __shared__ int pref[NPB];
    __shared__ int ts[256];
    const int t = threadIdx.x;
    const int b = blockIdx.x;
    const int s = b * CAP;
    const int e = s + min(cur[b], CAP);
    const int nb0 = b * NPB;
    const int nn = min(NPB, N - nb0);

    dcnt[t] = 0; dcnt[t + 256] = 0;
    __syncthreads();
    for (int i = s + t; i < e; i += 256)
        atomicAdd(&dcnt[(int)staged[i].x - nb0], 1);
    __syncthreads();

    int a0 = dcnt[2 * t], a1 = dcnt[2 * t + 1];
    ts[t] = a0 + a1;
    __syncthreads();
    for (int off = 1; off < 256; off <<= 1) {
        int u = (t >= off) ? ts[t - off] : 0;
        __syncthreads();
        ts[t] += u;
        __syncthreads();
    }
    int excl = (t > 0) ? ts[t - 1] : 0;
    pref[2 * t] = excl;
    pref[2 * t + 1] = excl + a0;
    __syncthreads();

    if (t < nn) {
        int bg = s + pref[t];
        rsbe[nb0 + t] = make_int2(bg, bg + dcnt[t]);
        invd[nb0 + t] = 1.0f / (float)max(dcnt[t], 1);
    }
    int t2 = t + 256;
    if (t2 < nn) {
        int bg = s + pref[t2];
        rsbe[nb0 + t2] = make_int2(bg, bg + dcnt[t2]);
        invd[nb0 + t2] = 1.0f / (float)max(dcnt[t2], 1);
    }
    __syncthreads();

    dcnt[t] = pref[t]; dcnt[t + 256] = pref[t + 256];
    __syncthreads();
    for (int i = s + t; i < e; i += 256) {
        uint2 p = staged[i];
        int r = atomicAdd(&dcnt[(int)p.x - nb0], 1);
        csr[s + r] = (int)p.y;
    }
}

// ================================================================ fused SAGE layer
// Agg phase: 64 groups x 8 LANES per row — fp8 row (128B) fetched as 8x uint4 =
// 8 lane-requests/row. Tail slots exec-masked (no wasted requests).
__global__ __launch_bounds__(512) void sage_layer(const unsigned short* __restrict__ Xin,
                                                  const unsigned char* __restrict__ X8in,
                                                  const unsigned short* __restrict__ WtF,
                                                  const float* __restrict__ bias,
                                                  const int* __restrict__ csr,
                                                  const int2* __restrict__ rsbe,
                                                  const float* __restrict__ invd,
                                                  unsigned short* __restrict__ Hout,
                                                  unsigned char* __restrict__ H8out, int N) {
    __shared__ unsigned short atile[128 * 128];   // 32 KiB agg tile, 16B-chunk XOR swizzle
    __shared__ unsigned short wlds[32 * 512];     // 32 KiB, one khalf of W

    const int t = threadIdx.x;
    const int r0 = blockIdx.x * 128;

    // stage W khalf0 (hidden under agg phase)
#pragma unroll
    for (int rep = 0; rep < 4; ++rep) {
        int e = rep * 4096 + t * 8;
        *(half8v*)&wlds[e] = *(const half8v*)(WtF + e);
    }

    // ---- aggregate phase: 64 groups x 8 lanes; 2 rows per group
    {
        const int grp = t >> 3, lane = t & 7;
#pragma unroll
        for (int it = 0; it < 2; ++it) {
            const int row = it * 64 + grp;        // 0..127
            const int node = r0 + row;
            float a[16];
#pragma unroll
            for (int j = 0; j < 16; ++j) a[j] = 0.f;
            if (node < N) {
                const int2 be = rsbe[node];
                const int beg = be.x, end = be.y;
                for (int base = beg; base < end; base += 8) {
                    const int cnt = end - base;   // >= 1
                    int idx[8];
#pragma unroll
                    for (int k = 0; k < 8; ++k) idx[k] = csr[min(base + k, end - 1)];
                    uint4 v[8];
#pragma unroll
                    for (int k = 0; k < 8; ++k) {
                        if (k < cnt)
                            v[k] = *(const uint4*)(X8in + ((size_t)idx[k] << 7) + lane * 16);
                    }
#pragma unroll
                    for (int k = 0; k < 8; ++k) {
                        if (k < cnt) acc16fp8(a, v[k]);
                    }
                }
                float sc = invd[node];
#pragma unroll
                for (int j = 0; j < 16; ++j) a[j] *= sc;
            }
            half8v o0, o1;
#pragma unroll
            for (int j = 0; j < 8; ++j) { o0[j] = (_Float16)a[j]; o1[j] = (_Float16)a[8 + j]; }
            const int c0 = (2 * lane) ^ (row & 7);      // 16B-chunk XOR swizzle
            const int c1 = (2 * lane + 1) ^ (row & 7);
            *(half8v*)&atile[row * 128 + c0 * 8] = o0;
            *(half8v*)&atile[row * 128 + c1 * 8] = o1;
        }
    }
    __syncthreads();   // atile ready AND wlds khalf0 ready

    const int wave = t >> 6, l = t & 63;
    const int trow = wave * 16 + (l & 15);        // row within tile / D^T node-row
    const int lk = (l >> 4) << 3;

    f32x4 acc[8];
#pragma unroll
    for (int nf = 0; nf < 8; ++nf) acc[nf] = (f32x4)(0.f);

    // khalf0: A = agg tile (LDS, swizzled), W = wlds
#pragma unroll
    for (int ks4 = 0; ks4 < 4; ++ks4) {
        const int chunk = (ks4 * 4 + (l >> 4)) ^ (trow & 7);
        half8v af = *(const half8v*)&atile[trow * 128 + chunk * 8];
#pragma unroll
        for (int nf = 0; nf < 8; ++nf) {
            half8v bh = *(const half8v*)&wlds[(nf * 4 + ks4) * 512 + l * 8];
            acc[nf] = __builtin_amdgcn_mfma_f32_16x16x32_f16(bh, af, acc[nf], 0, 0, 0);
        }
    }
    __syncthreads();
    // stage W khalf1
#pragma unroll
    for (int rep = 0; rep < 4; ++rep) {
        int e = rep * 4096 + t * 8;
        *(half8v*)&wlds[e] = *(const half8v*)(WtF + 16384 + e);
    }
    __syncthreads();

    // khalf1: A = X rows from global (fp16)
    {
        int row = r0 + trow;
        if (row >= N) row = N - 1;                // clamp: only pollutes discarded rows
#pragma unroll
        for (int ks4 = 0; ks4 < 4; ++ks4) {
            half8v af = *(const half8v*)(Xin + ((size_t)row << 7) + ks4 * 32 + lk);
#pragma unroll
            for (int nf = 0; nf < 8; ++nf) {
                half8v bh = *(const half8v*)&wlds[(nf * 4 + ks4) * 512 + l * 8];
                acc[nf] = __builtin_amdgcn_mfma_f32_16x16x32_f16(bh, af, acc[nf], 0, 0, 0);
            }
        }
    }

    // epilogue: relu + fp16 stores (8B) + fp8 stores (4B)
    const int jb = (l >> 4) << 2;
    const int orow = r0 + trow;
    if (orow < N) {
#pragma unroll
        for (int nf = 0; nf < 8; ++nf) {
            float4 bv = *(const float4*)&bias[nf * 16 + jb];
            float o0 = fmaxf(acc[nf][0] + bv.x, 0.f);
            float o1 = fmaxf(acc[nf][1] + bv.y, 0.f);
            float o2 = fmaxf(acc[nf][2] + bv.z, 0.f);
            float o3 = fmaxf(acc[nf][3] + bv.w, 0.f);
            uint2 st;
            st.x = (unsigned)f2h(o0) | ((unsigned)f2h(o1) << 16);
            st.y = (unsigned)f2h(o2) | ((unsigned)f2h(o3) << 16);
            *(uint2*)(Hout + ((size_t)orow << 7) + nf * 16 + jb) = st;
            *(unsigned*)(H8out + ((size_t)orow << 7) + nf * 16 + jb) = pk4fp8(o0, o1, o2, o3);
        }
    }
}

// ================================================================ fused agg3 + mean pool
// 32 groups x 8 lanes; fp8 gathers at 8 requests/row; fp16 own-rows.
__global__ __launch_bounds__(256) void agg3_pool(const unsigned short* __restrict__ H2,
                                                 const unsigned char* __restrict__ H28,
                                                 const int* __restrict__ csr,
                                                 const int2* __restrict__ rsbe,
                                                 const float* __restrict__ invd,
                                                 const int* __restrict__ gstart,
                                                 float* __restrict__ pa,
                                                 float* __restrict__ ph) {
    const int g = blockIdx.x >> 4;
    const int q = blockIdx.x & 15;
    const int s = gstart[g], e = gstart[g + 1];
    const int len = e - s;
    const int cs = s + (len * q) / 16;
    const int ce = s + (len * (q + 1)) / 16;
    const int t = threadIdx.x;
    const int grp = t >> 3, lane = t & 7;     // 32 groups x 8 lanes

    float aacc[16], hacc[16];
#pragma unroll
    for (int j = 0; j < 16; ++j) { aacc[j] = 0.f; hacc[j] = 0.f; }

    for (int node = cs + grp; node < ce; node += 32) {
        const int2 be = rsbe[node];
        const int beg = be.x, end = be.y;
        float a[16];
#pragma unroll
        for (int j = 0; j < 16; ++j) a[j] = 0.f;
        for (int base = beg; base < end; base += 8) {
            const int cnt = end - base;
            int idx[8];
#pragma unroll
            for (int k = 0; k < 8; ++k) idx[k] = csr[min(base + k, end - 1)];
            uint4 v[8];
#pragma unroll
            for (int k = 0; k < 8; ++k) {
                if (k < cnt)
                    v[k] = *(const uint4*)(H28 + ((size_t)idx[k] << 7) + lane * 16);
            }
#pragma unroll
            for (int k = 0; k < 8; ++k) {
                if (k < cnt) acc16fp8(a, v[k]);
            }
        }
        const float sc = invd[node];
#pragma unroll
        for (int j = 0; j < 16; ++j) aacc[j] += a[j] * sc;
        half8v own0 = *(const half8v*)(H2 + ((size_t)node << 7) + lane * 16);
        half8v own1 = *(const half8v*)(H2 + ((size_t)node << 7) + lane * 16 + 8);
        acc8h(hacc, own0);
        acc8h(hacc + 8, own1);
    }

    __shared__ float red[32][128];   // 16 KiB
#pragma unroll
    for (int j = 0; j < 16; ++j) red[grp][lane * 16 + j] = aacc[j];
    __syncthreads();
    if (t < 128) {
        float sum = 0.f;
#pragma unroll
        for (int k = 0; k < 32; ++k) sum += red[k][t];
        unsafeAtomicAdd(&pa[g * 128 + t], sum);
    }
    __syncthreads();
#pragma unroll
    for (int j = 0; j < 16; ++j) red[grp][lane * 16 + j] = hacc[j];
    __syncthreads();
    if (t < 128) {
        float sum = 0.f;
#pragma unroll
        for (int k = 0; k < 32; ++k) sum += red[k][t];
        unsafeAtomicAdd(&ph[g * 128 + t], sum);
    }
}

// ---------------------------------------------------------------- fused layer3 + readout (fp32)
__global__ __launch_bounds__(128) void final_fused(const float* __restrict__ pa,
                                                   const float* __restrict__ ph,
                                                   const float* __restrict__ gcnt,
                                                   const float* __restrict__ W3l,
                                                   const float* __restrict__ W3r,
                                                   const float* __restrict__ b3,
                                                   const float* __restrict__ Wout,
                                                   const float* __restrict__ bout,
                                                   float* __restrict__ out) {
    __shared__ float sA[FDIM], sH[FDIM], sT[FDIM];
    int g = blockIdx.x;
    int j = threadIdx.x;
    float inv = 1.0f / fmaxf(gcnt[g], 1.0f);
    sA[j] = pa[g * FDIM + j] * inv;
    sH[j] = ph[g * FDIM + j] * inv;
    __syncthreads();
    float acc = b3[j];
    for (int c = 0; c < FDIM; ++c)
        acc += sA[c] * W3l[c * FDIM + j] + sH[c] * W3r[c * FDIM + j];
    sT[j] = acc;
    __syncthreads();
    if (j < 10) {
        float o = bout[j];
        for (int c = 0; c < FDIM; ++c) o += sT[c] * Wout[c * 10 + j];
        out[g * 10 + j] = o;
    }
}

extern "C" void kernel_launch(void* const* d_in, const int* in_sizes, int n_in,
                              void* d_out, int out_size, void* d_ws, size_t ws_size,
                              hipStream_t stream) {
    const float* x     = (const float*)d_in[0];
    const int*   edge  = (const int*)d_in[1];
    const int*   batch = (const int*)d_in[2];
    const float* W1l = (const float*)d_in[3];
    const float* b1  = (const float*)d_in[4];
    const float* W1r = (const float*)d_in[5];
    const float* W2l = (const float*)d_in[6];
    const float* b2  = (const float*)d_in[7];
    const float* W2r = (const float*)d_in[8];
    const float* W3l = (const float*)d_in[9];
    const float* b3  = (const float*)d_in[10];
    const float* W3r = (const float*)d_in[11];
    const float* Wout = (const float*)d_in[12];
    const float* bout = (const float*)d_in[13];
    float* out = (float*)d_out;

    const int N = N_NODES_C;
    const int E = in_sizes[1] / 2;
    const int* src = edge;
    const int* tgt = edge + E;

    // ---- workspace layout
    char* ws = (char*)d_ws;
    size_t off = 0;
    auto carve = [&](size_t bytes) { char* p = ws + off; off += (bytes + 255) & ~(size_t)255; return p; };
    int2*  rsbe = (int2*)carve((size_t)N * 8);
    float* invd = (float*)carve((size_t)N * 4);
    int*   gstart = (int*)carve(65 * 4);
    float* gcnt = (float*)carve(64 * 4);
    float* pa   = (float*)carve((size_t)N_GRAPHS_C * FDIM * 4);
    float* ph   = (float*)carve((size_t)N_GRAPHS_C * FDIM * 4);
    int*   cur  = (int*)carve(NBUCK * 4);
    unsigned short* wt1 = (unsigned short*)carve(32768 * 2);
    unsigned short* wt2 = (unsigned short*)carve(32768 * 2);
    uint2* staged = (uint2*)carve((size_t)NBUCK * CAP * 8);
    int*   csr  = (int*)carve((size_t)NBUCK * CAP * 4);
    unsigned short* B0 = (unsigned short*)carve((size_t)N * FDIM * 2);
    unsigned short* B2 = (unsigned short*)carve((size_t)N * FDIM * 2);
    unsigned char* F0 = (unsigned char*)carve((size_t)N * FDIM);   // fp8 x -> later fp8 h2
    unsigned char* F1 = (unsigned char*)carve((size_t)N * FDIM);   // fp8 h1

    // ---- zero bucket cursors (tiny), then merged prep + scatter
    hipMemsetAsync(cur, 0, NBUCK * 4, stream);
    const int n8 = N * FDIM / 8;
    const int convBlocks = (n8 + 255) / 256;
    prep_scatter<<<SB + 256 + convBlocks + 1, 256, 0, stream>>>(
        src, tgt, cur, staged, E,
        x, B0, F0, n8,
        W1l, W1r, wt1, W2l, W2r, wt2,
        batch, gstart, gcnt, pa, ph, N, convBlocks);

    bucket_finalize<<<NBUCK, 256, 0, stream>>>(staged, cur, rsbe, invd, csr, N);

    const int layerGrid = (N + 127) / 128;

    // ---- layer 1 fused: h1 = relu([mean_N(x)|x]@W1+b1) -> B2 (fp16) + F1 (fp8)
    sage_layer<<<layerGrid, 512, 0, stream>>>(B0, F0, wt1, b1, csr, rsbe, invd, B2, F1, N);
    // ---- layer 2 fused: h2 = relu([mean_N(h1)|h1]@W2+b2) -> B0 (fp16) + F0 (fp8)
    sage_layer<<<layerGrid, 512, 0, stream>>>(B2, F1, wt2, b2, csr, rsbe, invd, B0, F0, N);

    // ---- layer 3 aggregation folded directly into pooling (fp8 gathers, fp16 own-rows)
    agg3_pool<<<N_GRAPHS_C * 16, 256, 0, stream>>>(B0, F0, csr, rsbe, invd, gstart, pa, ph);

    // ---- layer-3 GEMM (64 rows) + readout, full fp32
    final_fused<<<N_GRAPHS_C, 128, 0, stream>>>(pa, ph, gcnt, W3l, W3r, b3, Wout, bout, out);
}